// Round 1
// baseline (874.126 us; speedup 1.0000x reference)
//
#include <hip/hip_runtime.h>

// FastHelgasonMLP: out[b,t,o] = sum_i x[b,t,i] * W[o,i], W = U diag(S) V^T
// Factored: t = x @ (V*S)  [16384,1024], out = t @ U^T  [16384,4096]
// bf16 MFMA 16x16x32, fp32 accumulate. Threshold is bf16-grade (0.3375).

typedef __bf16 bf16;
typedef __bf16 bf16x4 __attribute__((ext_vector_type(4)));
typedef __bf16 bf16x8 __attribute__((ext_vector_type(8)));
typedef float  f32x4  __attribute__((ext_vector_type(4)));

#define M_DIM   16384   // B*T
#define IN_DIM  4096
#define OUT_DIM 4096
#define RK_DIM  1024

// ---------------------------------------------------------------------------
// Prep: blocks [0, xblocks)          : cast x fp32 -> bf16          (2048 f4/blk)
//       blocks [xblocks, +512)       : cast U fp32 -> bf16          (2048 f4/blk)
//       blocks [xblocks+512, +1024)  : VsT[r][i] = V[i][r]*S[r] bf16 (64x64 tile)
// ---------------------------------------------------------------------------
__global__ __launch_bounds__(256)
void prep_kernel(const float* __restrict__ x, const float* __restrict__ U,
                 const float* __restrict__ S, const float* __restrict__ V,
                 bf16* __restrict__ xb, bf16* __restrict__ Ub,
                 bf16* __restrict__ VsT, int xblocks)
{
    __shared__ float tile[64][68];   // +4 pad: conflict-free enough, only V path uses
    const int b = blockIdx.x;
    const int tid = threadIdx.x;

    if (b < xblocks) {
        const float4* xin = (const float4*)x;
        size_t base = (size_t)b * 2048 + tid;
        #pragma unroll
        for (int i = 0; i < 8; ++i) {
            float4 v = xin[base + (size_t)i * 256];
            bf16x4 o = { (bf16)v.x, (bf16)v.y, (bf16)v.z, (bf16)v.w };
            *(bf16x4*)&xb[(base + (size_t)i * 256) * 4] = o;
        }
    } else if (b < xblocks + 512) {
        const float4* uin = (const float4*)U;
        size_t base = (size_t)(b - xblocks) * 2048 + tid;
        #pragma unroll
        for (int i = 0; i < 8; ++i) {
            float4 v = uin[base + (size_t)i * 256];
            bf16x4 o = { (bf16)v.x, (bf16)v.y, (bf16)v.z, (bf16)v.w };
            *(bf16x4*)&Ub[(base + (size_t)i * 256) * 4] = o;
        }
    } else {
        const int vb   = b - (xblocks + 512);
        const int rblk = vb & 15;        // 1024/64 = 16 tiles along rank
        const int iblk = vb >> 4;        // 4096/64 = 64 tiles along in
        const int r0 = rblk * 64, i0 = iblk * 64;

        const int tr  = tid >> 4;        // 0..15
        const int tc4 = (tid & 15) * 4;  // 0..60
        #pragma unroll
        for (int j = 0; j < 4; ++j) {
            float4 v = *(const float4*)&V[(size_t)(i0 + tr + j * 16) * RK_DIM + r0 + tc4];
            tile[tr + j * 16][tc4 + 0] = v.x;
            tile[tr + j * 16][tc4 + 1] = v.y;
            tile[tr + j * 16][tc4 + 2] = v.z;
            tile[tr + j * 16][tc4 + 3] = v.w;
        }
        __syncthreads();
        const int rr  = tid >> 2;        // 0..63 (local rank row)
        const int ic0 = (tid & 3) * 16;  // 0..48 (local in col base)
        const float s = S[r0 + rr];
        #pragma unroll
        for (int j = 0; j < 4; ++j) {
            bf16x4 o;
            #pragma unroll
            for (int q = 0; q < 4; ++q)
                o[q] = (bf16)(tile[ic0 + j * 4 + q][rr] * s);
            *(bf16x4*)&VsT[(size_t)(r0 + rr) * IN_DIM + i0 + ic0 + j * 4] = o;
        }
    }
}

// ---------------------------------------------------------------------------
// gemm_bt: C[M,N] = A[M,K] * B[N,K]^T,  bf16 inputs (A optionally fp32,
// converted during staging), fp32 accumulate, C stored as CT.
// Block = 256 thr (4 waves 2x2), tile 128x128, BK=32, MFMA f32_16x16x32_bf16.
// LDS stride 40 (=80B, multiple of 16B for ds_read_b128; 2-way bank alias = free).
// ---------------------------------------------------------------------------
template <typename AT, typename CT>
__global__ __launch_bounds__(256)
void gemm_bt(const AT* __restrict__ A, const bf16* __restrict__ B,
             CT* __restrict__ C, int M, int N, int K)
{
    __shared__ bf16 As[128][40];
    __shared__ bf16 Bs[128][40];

    const int tid  = threadIdx.x;
    const int lane = tid & 63;
    const int wave = tid >> 6;
    const int wrow = wave >> 1;      // 0..1
    const int wcol = wave & 1;       // 0..1
    const int n0 = blockIdx.x * 128;
    const int m0 = blockIdx.y * 128;

    f32x4 acc[4][4];
    #pragma unroll
    for (int mi = 0; mi < 4; ++mi)
        #pragma unroll
        for (int ni = 0; ni < 4; ++ni)
            acc[mi][ni] = (f32x4){0.f, 0.f, 0.f, 0.f};

    const int fr = lane & 15;            // fragment row (m or n)
    const int kq = (lane >> 4) * 8;      // fragment k base

    for (int kk = 0; kk < K; kk += 32) {
        __syncthreads();
        // ---- stage A tile (128 x 32) ----
        if constexpr (sizeof(AT) == 4) {
            // fp32 A: 4096 floats = 1024 float4 chunks, 4 per thread
            #pragma unroll
            for (int i = 0; i < 4; ++i) {
                int c = tid + i * 256;
                int row = c >> 3, kc = (c & 7) * 4;
                float4 v = *(const float4*)&A[(size_t)(m0 + row) * K + kk + kc];
                bf16x4 o = { (bf16)v.x, (bf16)v.y, (bf16)v.z, (bf16)v.w };
                *(bf16x4*)&As[row][kc] = o;
            }
        } else {
            // bf16 A: 4096 bf16 = 512 x8 chunks, 2 per thread
            #pragma unroll
            for (int i = 0; i < 2; ++i) {
                int c = tid + i * 256;
                int row = c >> 2, kc = (c & 3) * 8;
                *(bf16x8*)&As[row][kc] = *(const bf16x8*)&A[(size_t)(m0 + row) * K + kk + kc];
            }
        }
        // ---- stage B tile (128 x 32, B is [N,K] row-major) ----
        #pragma unroll
        for (int i = 0; i < 2; ++i) {
            int c = tid + i * 256;
            int row = c >> 2, kc = (c & 3) * 8;
            *(bf16x8*)&Bs[row][kc] = *(const bf16x8*)&B[(size_t)(n0 + row) * K + kk + kc];
        }
        __syncthreads();

        // ---- fragments: A[m=lane&15][k=(lane>>4)*8+j], B^T same addressing ----
        bf16x8 af[4], bfg[4];
        #pragma unroll
        for (int i = 0; i < 4; ++i) {
            af[i]  = *(const bf16x8*)&As[wrow * 64 + i * 16 + fr][kq];
            bfg[i] = *(const bf16x8*)&Bs[wcol * 64 + i * 16 + fr][kq];
        }
        #pragma unroll
        for (int mi = 0; mi < 4; ++mi)
            #pragma unroll
            for (int ni = 0; ni < 4; ++ni)
                acc[mi][ni] = __builtin_amdgcn_mfma_f32_16x16x32_bf16(
                    af[mi], bfg[ni], acc[mi][ni], 0, 0, 0);
    }

    // ---- epilogue: C/D layout col=lane&15, row=(lane>>4)*4+reg (m89/m91) ----
    const int ccol  = n0 + wcol * 64 + fr;
    const int crow0 = m0 + wrow * 64 + (lane >> 4) * 4;
    #pragma unroll
    for (int mi = 0; mi < 4; ++mi)
        #pragma unroll
        for (int ni = 0; ni < 4; ++ni)
            #pragma unroll
            for (int r = 0; r < 4; ++r)
                C[(size_t)(crow0 + mi * 16 + r) * N + ccol + ni * 16] =
                    (CT)acc[mi][ni][r];
}

// ---------------------------------------------------------------------------
extern "C" void kernel_launch(void* const* d_in, const int* in_sizes, int n_in,
                              void* d_out, int out_size, void* d_ws, size_t ws_size,
                              hipStream_t stream)
{
    const float* x = (const float*)d_in[0];   // [4,4096,4096]
    const float* U = (const float*)d_in[1];   // [4096,1024]
    const float* S = (const float*)d_in[2];   // [1024]
    const float* V = (const float*)d_in[3];   // [4096,1024]
    float* out = (float*)d_out;               // [4,4096,4096]

    const size_t SZ_XB  = (size_t)M_DIM * IN_DIM * 2;   // 128 MiB
    const size_t SZ_UB  = (size_t)OUT_DIM * RK_DIM * 2; //   8 MiB
    const size_t SZ_VST = (size_t)RK_DIM * IN_DIM * 2;  //   8 MiB
    const size_t SZ_T   = (size_t)M_DIM * RK_DIM * 2;   //  32 MiB

    char* p = (char*)d_ws;
    const bool full = ws_size >= SZ_XB + SZ_UB + SZ_VST + SZ_T;
    bf16* xb = nullptr;
    if (full) { xb = (bf16*)p; p += SZ_XB; }
    bf16* Ub  = (bf16*)p; p += SZ_UB;
    bf16* VsT = (bf16*)p; p += SZ_VST;
    bf16* t   = (bf16*)p;

    const int xblocks = full ? 8192 : 0;
    prep_kernel<<<xblocks + 512 + 1024, 256, 0, stream>>>(
        x, U, S, V, full ? xb : Ub, Ub, VsT, xblocks);

    // GEMM1: t[M, RK] = xb[M, IN] * VsT[RK, IN]^T
    if (full)
        gemm_bt<bf16, bf16><<<dim3(RK_DIM / 128, M_DIM / 128), 256, 0, stream>>>(
            xb, VsT, t, M_DIM, RK_DIM, IN_DIM);
    else
        gemm_bt<float, bf16><<<dim3(RK_DIM / 128, M_DIM / 128), 256, 0, stream>>>(
            x, VsT, t, M_DIM, RK_DIM, IN_DIM);

    // GEMM2: out[M, OUT] = t[M, RK] * Ub[OUT, RK]^T
    gemm_bt<bf16, float><<<dim3(OUT_DIM / 128, M_DIM / 128), 256, 0, stream>>>(
        t, Ub, out, M_DIM, OUT_DIM, RK_DIM);
}